// Round 12
// baseline (284.243 us; speedup 1.0000x reference)
//
#include <hip/hip_runtime.h>
#include <hip/hip_fp16.h>

// GCN 2-layer inference, N=100000, E=1600000, F_IN=100, H=128, C=47.
// R15 (base R14, 266.6us): (a) nontemporal loads for read-once streams
// (ep in aggs, ei in scatter) so they stop evicting the gather tables from
// the 4MB/XCD L2 (aggs are L2-miss-path bound: FETCH 110MB at ~16cy/line =
// MSHR limit; only miss REDUCTION helps); (b) kernel chain 8 -> 5+memset:
// init_small -> hipMemsetAsync (gbcur starts at 0, scatter adds b*BCAP
// locally); bucket_place fused into countscan (pairs L2-hot from count
// phase; rowbeg recomputed from in-LDS scan, cur[] third LDS array).
// gemms (MFMA) and agg bodies unchanged from R14. absmax expect 0.0078.

typedef unsigned int uint32;
typedef float f32x2 __attribute__((ext_vector_type(2)));
typedef __fp16 fp16x2 __attribute__((ext_vector_type(2)));
typedef _Float16 h2v __attribute__((ext_vector_type(2)));
typedef _Float16 f16x8 __attribute__((ext_vector_type(8)));
typedef float f32x4 __attribute__((ext_vector_type(4)));

constexpr int N    = 100000;
constexpr int E    = 1600000;
constexpr int FIN  = 100;
constexpr int HD   = 128;
constexpr int C    = 47;
constexpr int C48  = 48;
constexpr int EN_CAP = E + 8 * N;    // padded edge-slot upper bound

// bucketed CSR build
constexpr int NPB   = 512;                          // nodes per bucket (dst>>9)
constexpr int NBUCK = (N + NPB - 1) / NPB;          // 196
constexpr int ABLK  = 400;                          // scatter blocks
constexpr int EPB   = E / ABLK;                     // 4000 edges per block
constexpr int BCAP  = 16384;                        // bucket capacity (mean 8192 + 91 sigma)

// ---------- fp8 / fp16 helpers ----------

__device__ __forceinline__ uint32 pack_fp8x4(float x, float y, float z, float w) {
    int r = __builtin_amdgcn_cvt_pk_fp8_f32(x, y, 0, false);   // bytes 0,1
    r = __builtin_amdgcn_cvt_pk_fp8_f32(z, w, r, true);        // bytes 2,3
    return (uint32)r;
}

__device__ __forceinline__ void acc_fp8x4(uint32 v, float& a0, float& a1,
                                          float& a2, float& a3) {
    f32x2 lo = __builtin_amdgcn_cvt_pk_f32_fp8((int)v, false);
    f32x2 hi = __builtin_amdgcn_cvt_pk_f32_fp8((int)v, true);
    a0 += lo[0]; a1 += lo[1]; a2 += hi[0]; a3 += hi[1];
}

__device__ __forceinline__ uint32 pk16(float a, float b) {
    union { fp16x2 h; uint32 u; } x;
    x.h = __builtin_amdgcn_cvt_pkrtz(a, b);    // v_cvt_pkrtz_f16_f32
    return x.u;
}

// ---------- CSR build: 2 kernels (+memset), no serial passes ----------

// LDS histogram + per-bucket segment alloc + scatter packed (dstLocal<<20|src).
// gbcur zero-initialized by memset; base = b*BCAP + atomic offset.
__global__ __launch_bounds__(256) void bucket_scatter2(const int* __restrict__ ei,
                                                       int* __restrict__ gbcur,
                                                       uint32* __restrict__ pairs) {
    __shared__ int h[NBUCK];
    __shared__ int baseL[NBUCK];
    __shared__ int cur[NBUCK];
    int t = threadIdx.x, blk = blockIdx.x;
    for (int i = t; i < NBUCK; i += 256) h[i] = 0;
    __syncthreads();
    int base = blk * EPB;
    for (int i = t; i < EPB; i += 256) {
        int d = __builtin_nontemporal_load(ei + E + base + i);
        atomicAdd(&h[d >> 9], 1);
    }
    __syncthreads();
    for (int i = t; i < NBUCK; i += 256) {
        baseL[i] = i * BCAP + atomicAdd(&gbcur[i], h[i]);
        cur[i] = 0;
    }
    __syncthreads();
    for (int i = t; i < EPB; i += 256) {
        int s = __builtin_nontemporal_load(ei + base + i);
        int d = __builtin_nontemporal_load(ei + E + base + i);
        int b = d >> 9;
        int off = atomicAdd(&cur[b], 1);
        pairs[baseL[b] + off] = (uint32)s | ((uint32)(d & (NPB - 1)) << 20);
    }
}

// count (LDS atomics) + 512-entry cap-scan + atomic CSR-base alloc ->
// rowptr/rowend/dinv/self-loop/pads, THEN place edges (pairs L2-hot).
__global__ __launch_bounds__(256) void bucket_countplace(const uint32* __restrict__ pairs,
                                                         const int* __restrict__ gbcur,
                                                         int* __restrict__ galloc,
                                                         int* __restrict__ rowptr,
                                                         int* __restrict__ rowend,
                                                         float* __restrict__ dinv,
                                                         int* __restrict__ ep) {
    __shared__ int c[NPB];     // degrees (kept through place phase)
    __shared__ int sm[NPB];    // inclusive cap-scan (kept)
    __shared__ int cur[NPB];   // place cursors
    __shared__ int sbase;
    int b = blockIdx.x, t = threadIdx.x;
    for (int i = t; i < NPB; i += 256) c[i] = 1;   // self loop
    __syncthreads();
    int pbase = b * BCAP;
    int blen = gbcur[b];
    for (int i = t; i < blen; i += 256)
        atomicAdd(&c[pairs[pbase + i] >> 20], 1);
    __syncthreads();
    int node0 = b * NPB;
    int i0 = t, i1 = t + 256;
    int n0 = node0 + i0, n1 = node0 + i1;
    int deg0 = (n0 < N) ? c[i0] : 0;
    int deg1 = (n1 < N) ? c[i1] : 0;
    int cap0 = (deg0 + 7) & ~7;     // 0 stays 0 for invalid nodes
    int cap1 = (deg1 + 7) & ~7;
    sm[i0] = cap0; sm[i1] = cap1;
    __syncthreads();
    for (int off = 1; off < NPB; off <<= 1) {
        int o0 = sm[i0], o1 = sm[i1];
        int a0 = (i0 >= off) ? sm[i0 - off] : 0;
        int a1 = (i1 >= off) ? sm[i1 - off] : 0;
        __syncthreads();
        sm[i0] = o0 + a0; sm[i1] = o1 + a1;
        __syncthreads();
    }
    if (t == 0) sbase = atomicAdd(galloc, sm[NPB - 1]);
    __syncthreads();
    int gb = sbase;
    if (n0 < N) {
        int beg = gb + sm[i0] - cap0;
        rowptr[n0] = beg; rowend[n0] = beg + cap0;
        dinv[n0] = rsqrtf((float)deg0);
        ep[beg] = n0;                                  // self loop at slot 0
        for (int k = deg0; k < cap0; ++k) ep[beg + k] = N;  // pads -> zero row
    }
    if (n1 < N) {
        int beg = gb + sm[i1] - cap1;
        rowptr[n1] = beg; rowend[n1] = beg + cap1;
        dinv[n1] = rsqrtf((float)deg1);
        ep[beg] = n1;
        for (int k = deg1; k < cap1; ++k) ep[beg + k] = N;
    }
    // place phase: cursors start at 1 (slot 0 = self loop)
    cur[i0] = 1; cur[i1] = 1;
    __syncthreads();
    for (int i = t; i < blen; i += 256) {
        uint32 p = pairs[pbase + i];
        int dl = p >> 20;
        int slot = atomicAdd(&cur[dl], 1);
        int rowbeg = gb + sm[dl] - ((c[dl] + 7) & ~7);
        ep[rowbeg + slot] = (int)(p & 0xFFFFF);
    }
}

// ---------- GEMM1 (MFMA): xw8[N+1,32 dwords] fp8 = dinv[n]*(x @ W1) ----------

__global__ __launch_bounds__(256) void gemm1(const float* __restrict__ x,
                                             const float* __restrict__ W1,
                                             const float* __restrict__ dinv,
                                             uint32* __restrict__ xw8) {
    __shared__ uint32 sA[8192];   // 32 KB, frag-linear: [(nt*4+ks)*256 + l*4 + d]
    int tx = threadIdx.x;

    for (int idx = tx; idx < 8192; idx += 256) {
        int slot = idx >> 8;               // nt*4 + ks
        int rem  = idx & 255;
        int l = rem >> 2, d = rem & 3;
        int nt = slot >> 2, ks = slot & 3;
        int n = nt * 16 + (l & 15);
        int k = ks * 32 + (l >> 4) * 8 + 2 * d;
        float va = (k < FIN)     ? W1[k * HD + n]       : 0.f;
        float vb = (k + 1 < FIN) ? W1[(k + 1) * HD + n] : 0.f;
        sA[idx] = pk16(va, vb);
    }
    __syncthreads();

    int l = tx & 63, w = tx >> 6;
    int m = l & 15, oct = l >> 4;
    size_t node0 = (size_t)blockIdx.x * 128 + (size_t)w * 32;
    size_t nA = node0 + m;          // node-tile 0
    size_t nB = node0 + 16 + m;     // node-tile 1

    f32x4 acc0[8], acc1[8];
#pragma unroll
    for (int nt = 0; nt < 8; ++nt) {
        acc0[nt] = (f32x4){0.f, 0.f, 0.f, 0.f};
        acc1[nt] = (f32x4){0.f, 0.f, 0.f, 0.f};
    }

#pragma unroll
    for (int ks = 0; ks < 4; ++ks) {
        int k0 = ks * 32 + oct * 8;
        float4 fa0 = make_float4(0.f, 0.f, 0.f, 0.f), fa1 = fa0;
        float4 fb0 = make_float4(0.f, 0.f, 0.f, 0.f), fb1 = fb0;
        if (nA < (size_t)N) {
            const float* xr = x + nA * FIN;
            if (k0 < FIN)     fa0 = *(const float4*)(xr + k0);
            if (k0 + 4 < FIN) fa1 = *(const float4*)(xr + k0 + 4);
        }
        if (nB < (size_t)N) {
            const float* xr = x + nB * FIN;
            if (k0 < FIN)     fb0 = *(const float4*)(xr + k0);
            if (k0 + 4 < FIN) fb1 = *(const float4*)(xr + k0 + 4);
        }
        union { uint4 u; f16x8 h; } b0, b1;
        b0.u = make_uint4(pk16(fa0.x, fa0.y), pk16(fa0.z, fa0.w),
                          pk16(fa1.x, fa1.y), pk16(fa1.z, fa1.w));
        b1.u = make_uint4(pk16(fb0.x, fb0.y), pk16(fb0.z, fb0.w),
                          pk16(fb1.x, fb1.y), pk16(fb1.z, fb1.w));
#pragma unroll
        for (int nt = 0; nt < 8; ++nt) {
            union { uint4 u; f16x8 h; } a;
            a.u = *(const uint4*)&sA[(nt * 4 + ks) * 256 + l * 4];
            acc0[nt] = __builtin_amdgcn_mfma_f32_16x16x32_f16(a.h, b0.h, acc0[nt], 0, 0, 0);
            acc1[nt] = __builtin_amdgcn_mfma_f32_16x16x32_f16(a.h, b1.h, acc1[nt], 0, 0, 0);
        }
    }

    if (nA <= (size_t)N) {
        float dv = (nA < (size_t)N) ? dinv[nA] : 0.f;
#pragma unroll
        for (int nt = 0; nt < 8; ++nt) {
            f32x4 v = acc0[nt];
            uint32 p = (nA < (size_t)N)
                ? pack_fp8x4(v[0] * dv, v[1] * dv, v[2] * dv, v[3] * dv) : 0u;
            xw8[nA * 32 + nt * 4 + oct] = p;
        }
    }
    if (nB <= (size_t)N) {
        float dv = (nB < (size_t)N) ? dinv[nB] : 0.f;
#pragma unroll
        for (int nt = 0; nt < 8; ++nt) {
            f32x4 v = acc1[nt];
            uint32 p = (nB < (size_t)N)
                ? pack_fp8x4(v[0] * dv, v[1] * dv, v[2] * dv, v[3] * dv) : 0u;
            xw8[nB * 32 + nt * 4 + oct] = p;
        }
    }
}

// ---------- agg1: h[n] (fp16) = relu(b1 + dinv[n] * sum_j xw8[src_j]) ----------
// 16-edge unroll, 8-edge tail; ep via nontemporal loads (read-once stream).

__global__ __launch_bounds__(256) void agg1(const uint32* __restrict__ xw8,
                                            const int* __restrict__ rowptr,
                                            const int* __restrict__ rowend,
                                            const int* __restrict__ ep,
                                            const float* __restrict__ dinv,
                                            const float* __restrict__ b1,
                                            __half* __restrict__ h) {
    int node = blockIdx.x * 4 + (threadIdx.x >> 6);
    if (node >= N) return;
    int lane = threadIdx.x & 63;
    int hf = lane >> 5;      // which edge of the pair
    int q  = lane & 31;      // dword within 128B row -> dims q*4..q*4+3
    int beg = rowptr[node], end = rowend[node];   // cap, multiple of 8
    float a0 = 0.f, a1 = 0.f, a2 = 0.f, a3 = 0.f;
    int j = beg;
    for (; j + 16 <= end; j += 16) {
        int s0 = __builtin_nontemporal_load(ep + j + hf);
        int s1 = __builtin_nontemporal_load(ep + j + 2 + hf);
        int s2 = __builtin_nontemporal_load(ep + j + 4 + hf);
        int s3 = __builtin_nontemporal_load(ep + j + 6 + hf);
        int s4 = __builtin_nontemporal_load(ep + j + 8 + hf);
        int s5 = __builtin_nontemporal_load(ep + j + 10 + hf);
        int s6 = __builtin_nontemporal_load(ep + j + 12 + hf);
        int s7 = __builtin_nontemporal_load(ep + j + 14 + hf);
        uint32 v0 = xw8[(size_t)s0 * 32 + q];
        uint32 v1 = xw8[(size_t)s1 * 32 + q];
        uint32 v2 = xw8[(size_t)s2 * 32 + q];
        uint32 v3 = xw8[(size_t)s3 * 32 + q];
        uint32 v4 = xw8[(size_t)s4 * 32 + q];
        uint32 v5 = xw8[(size_t)s5 * 32 + q];
        uint32 v6 = xw8[(size_t)s6 * 32 + q];
        uint32 v7 = xw8[(size_t)s7 * 32 + q];
        acc_fp8x4(v0, a0, a1, a2, a3);
        acc_fp8x4(v1, a0, a1, a2, a3);
        acc_fp8x4(v2, a0, a1, a2, a3);
        acc_fp8x4(v3, a0, a1, a2, a3);
        acc_fp8x4(v4, a0, a1, a2, a3);
        acc_fp8x4(v5, a0, a1, a2, a3);
        acc_fp8x4(v6, a0, a1, a2, a3);
        acc_fp8x4(v7, a0, a1, a2, a3);
    }
    if (j < end) {   // 8 remaining
        int s0 = __builtin_nontemporal_load(ep + j + hf);
        int s1 = __builtin_nontemporal_load(ep + j + 2 + hf);
        int s2 = __builtin_nontemporal_load(ep + j + 4 + hf);
        int s3 = __builtin_nontemporal_load(ep + j + 6 + hf);
        uint32 v0 = xw8[(size_t)s0 * 32 + q];
        uint32 v1 = xw8[(size_t)s1 * 32 + q];
        uint32 v2 = xw8[(size_t)s2 * 32 + q];
        uint32 v3 = xw8[(size_t)s3 * 32 + q];
        acc_fp8x4(v0, a0, a1, a2, a3);
        acc_fp8x4(v1, a0, a1, a2, a3);
        acc_fp8x4(v2, a0, a1, a2, a3);
        acc_fp8x4(v3, a0, a1, a2, a3);
    }
    a0 += __shfl_xor(a0, 32);
    a1 += __shfl_xor(a1, 32);
    a2 += __shfl_xor(a2, 32);
    a3 += __shfl_xor(a3, 32);
    if (hf == 0) {
        float dv = dinv[node];
        float4 bb = *(const float4*)&b1[q * 4];
        float r0 = fmaxf(fmaf(dv, a0, bb.x), 0.f);
        float r1 = fmaxf(fmaf(dv, a1, bb.y), 0.f);
        float r2 = fmaxf(fmaf(dv, a2, bb.z), 0.f);
        float r3 = fmaxf(fmaf(dv, a3, bb.w), 0.f);
        union { __half2 h2[2]; uint2 u; } p;
        p.h2[0] = __floats2half2_rn(r0, r1);
        p.h2[1] = __floats2half2_rn(r2, r3);
        *(uint2*)&h[(size_t)node * HD + q * 4] = p.u;
    }
}

// ---------- GEMM2 (MFMA): xw2h[N+1,48] fp16 = dinv[n]*(h @ W2), col47=0 ----------

__global__ __launch_bounds__(256) void gemm2(const uint32* __restrict__ hh,
                                             const float* __restrict__ W2,
                                             const float* __restrict__ dinv,
                                             __half* __restrict__ xw2h) {
    __shared__ uint32 sA[3072];   // 12 KB: [(nt*4+ks)*256 + l*4 + d]
    int tx = threadIdx.x;

    for (int idx = tx; idx < 3072; idx += 256) {
        int slot = idx >> 8;               // nt*4 + ks
        int rem  = idx & 255;
        int l = rem >> 2, d = rem & 3;
        int nt = slot >> 2, ks = slot & 3;
        int c = nt * 16 + (l & 15);
        int k = ks * 32 + (l >> 4) * 8 + 2 * d;
        float va = (c < C) ? W2[k * C + c]       : 0.f;
        float vb = (c < C) ? W2[(k + 1) * C + c] : 0.f;
        sA[idx] = pk16(va, vb);
    }
    __syncthreads();

    int l = tx & 63, w = tx >> 6;
    int m = l & 15, oct = l >> 4;
    size_t node0 = (size_t)blockIdx.x * 128 + (size_t)w * 32;
    size_t nA = node0 + m;
    size_t nB = node0 + 16 + m;

    f32x4 acc0[3], acc1[3];
#pragma unroll
    for (int nt = 0; nt < 3; ++nt) {
        acc0[nt] = (f32x4){0.f, 0.f, 0.f, 0.f};
        acc1[nt] = (f32x4){0.f, 0.f, 0.f, 0.f};
    }

#pragma unroll
    for (int ks = 0; ks < 4; ++ks) {
        union { uint4 u; f16x8 h; } b0, b1;
        b0.u = (nA < (size_t)N) ? *(const uint4*)&hh[nA * 64 + ks * 16 + oct * 4]
                                : make_uint4(0u, 0u, 0u, 0u);
        b1.u = (nB < (size_t)N) ? *(const uint4*)&hh[nB * 64 + ks * 16 + oct * 4]
                                : make_uint4(0u, 0u, 0u, 0u);
#pragma unroll
        for (int nt = 0; nt < 3; ++nt) {
            union { uint4 u; f16x8 h; } a;
            a.u = *(const uint4*)&sA[(nt * 4 + ks) * 256 + l * 4];
            acc0[nt] = __builtin_amdgcn_mfma_f32_16x16x32_f16(a.h, b0.h, acc0[nt], 0, 0, 0);
            acc1[nt] = __builtin_amdgcn_mfma_f32_16x16x32_f16(a.h, b1.h, acc1[nt], 0, 0, 0);
        }
    }

    if (nA <= (size_t)N) {
        float dv = (nA < (size_t)N) ? dinv[nA] : 0.f;
#pragma unroll
        for (int nt = 0; nt < 3; ++nt) {
            int c0 = nt * 16 + oct * 4;
            f32x4 v = acc0[nt];
            uint2 p = make_uint2(pk16(v[0] * dv, v[1] * dv),
                                 pk16(v[2] * dv, v[3] * dv));
            *(uint2*)&xw2h[nA * C48 + c0] = p;   // col47: A-pad=0 -> writes 0
        }
    }
    if (nB <= (size_t)N) {
        float dv = (nB < (size_t)N) ? dinv[nB] : 0.f;
#pragma unroll
        for (int nt = 0; nt < 3; ++nt) {
            int c0 = nt * 16 + oct * 4;
            f32x4 v = acc1[nt];
            uint2 p = make_uint2(pk16(v[0] * dv, v[1] * dv),
                                 pk16(v[2] * dv, v[3] * dv));
            *(uint2*)&xw2h[nB * C48 + c0] = p;
        }
    }
}

// ---------- agg2: out[n] = b2 + dinv[n] * sum_j xw2[src_j] ----------
// 16-edge unroll, 8-edge tail; ep via nontemporal loads.

__global__ __launch_bounds__(256) void agg2(const uint32* __restrict__ xw2d,
                                            const int* __restrict__ rowptr,
                                            const int* __restrict__ rowend,
                                            const int* __restrict__ ep,
                                            const float* __restrict__ dinv,
                                            const float* __restrict__ b2,
                                            float* __restrict__ out) {
    int node = blockIdx.x * 4 + (threadIdx.x >> 6);
    if (node >= N) return;
    int lane = threadIdx.x & 63;
    int hf = lane >> 5;      // which edge of the pair
    int q  = lane & 31;      // dword within row (only q<24 valid)
    bool act = q < 24;
    int beg = rowptr[node], end = rowend[node];   // cap, multiple of 8
    float a0 = 0.f, a1 = 0.f;
    int j = beg;
    for (; j + 16 <= end; j += 16) {
        int s0 = __builtin_nontemporal_load(ep + j + hf);
        int s1 = __builtin_nontemporal_load(ep + j + 2 + hf);
        int s2 = __builtin_nontemporal_load(ep + j + 4 + hf);
        int s3 = __builtin_nontemporal_load(ep + j + 6 + hf);
        int s4 = __builtin_nontemporal_load(ep + j + 8 + hf);
        int s5 = __builtin_nontemporal_load(ep + j + 10 + hf);
        int s6 = __builtin_nontemporal_load(ep + j + 12 + hf);
        int s7 = __builtin_nontemporal_load(ep + j + 14 + hf);
        if (act) {
            uint32 v0 = xw2d[(size_t)s0 * 24 + q];
            uint32 v1 = xw2d[(size_t)s1 * 24 + q];
            uint32 v2 = xw2d[(size_t)s2 * 24 + q];
            uint32 v3 = xw2d[(size_t)s3 * 24 + q];
            uint32 v4 = xw2d[(size_t)s4 * 24 + q];
            uint32 v5 = xw2d[(size_t)s5 * 24 + q];
            uint32 v6 = xw2d[(size_t)s6 * 24 + q];
            uint32 v7 = xw2d[(size_t)s7 * 24 + q];
            float2 f;
            f = __half22float2(*(const __half2*)&v0); a0 += f.x; a1 += f.y;
            f = __half22float2(*(const __half2*)&v1); a0 += f.x; a1 += f.y;
            f = __half22float2(*(const __half2*)&v2); a0 += f.x; a1 += f.y;
            f = __half22float2(*(const __half2*)&v3); a0 += f.x; a1 += f.y;
            f = __half22float2(*(const __half2*)&v4); a0 += f.x; a1 += f.y;
            f = __half22float2(*(const __half2*)&v5); a0 += f.x; a1 += f.y;
            f = __half22float2(*(const __half2*)&v6); a0 += f.x; a1 += f.y;
            f = __half22float2(*(const __half2*)&v7); a0 += f.x; a1 += f.y;
        }
    }
    if (j < end) {   // 8 remaining
        int s0 = __builtin_nontemporal_load(ep + j + hf);
        int s1 = __builtin_nontemporal_load(ep + j + 2 + hf);
        int s2 = __builtin_nontemporal_load(ep + j + 4 + hf);
        int s3 = __builtin_nontemporal_load(ep + j + 6 + hf);
        if (act) {
            uint32 v0 = xw2d[(size_t)s0 * 24 + q];
            uint32 v1 = xw2d[(size_t)s1 * 24 + q];
            uint32 v2 = xw2d[(size_t)s2 * 24 + q];
            uint32 v3 = xw2d[(size_t)s3 * 24 + q];
            float2 f;
            f = __half22float2(*(const __half2*)&v0); a0 += f.x; a1 += f.y;
            f = __half22float2(*(const __half2*)&v1); a0 += f.x; a1 += f.y;
            f = __half22float2(*(const __half2*)&v2); a0 += f.x; a1 += f.y;
            f = __half22float2(*(const __half2*)&v3); a0 += f.x; a1 += f.y;
        }
    }
    a0 += __shfl_xor(a0, 32);
    a1 += __shfl_xor(a1, 32);
    if (hf == 0 && act) {
        float dv = dinv[node];
        int c = q * 2;
        out[(size_t)node * C + c] = fmaf(dv, a0, b2[c]);
        if (c + 1 < C) out[(size_t)node * C + c + 1] = fmaf(dv, a1, b2[c + 1]);
    }
}

extern "C" void kernel_launch(void* const* d_in, const int* in_sizes, int n_in,
                              void* d_out, int out_size, void* d_ws, size_t ws_size,
                              hipStream_t stream) {
    const float* x  = (const float*)d_in[0];
    const int*   ei = (const int*)d_in[1];
    const float* W1 = (const float*)d_in[2];
    const float* b1 = (const float*)d_in[3];
    const float* W2 = (const float*)d_in[4];
    const float* b2 = (const float*)d_in[5];
    float* out = (float*)d_out;

    size_t off = 0;
    auto alloc = [&](size_t bytes) {
        void* p = (char*)d_ws + off;
        off += (bytes + 255) & ~(size_t)255;
        return p;
    };
    int*    gmeta   = (int*)alloc((size_t)(NBUCK + 64) * 4);  // gbcur[NBUCK] + galloc
    uint32* pairs   = (uint32*)alloc((size_t)NBUCK * BCAP * 4);   // 12.8 MB
    int*    rowptr  = (int*)alloc((size_t)N * 4);
    int*    rowend  = (int*)alloc((size_t)N * 4);
    float*  dinv    = (float*)alloc((size_t)N * 4);
    int*    ep      = (int*)alloc((size_t)EN_CAP * 4);
    uint32* xw8     = (uint32*)alloc((size_t)(N + 1) * 32 * 4);   // fp8 [N+1][128]
    __half* hh      = (__half*)alloc((size_t)N * HD * 2);
    __half* xw2h    = (__half*)alloc((size_t)(N + 1) * C48 * 2);  // fp16 [N+1][48]
    (void)ws_size;
    int* gbcur  = gmeta;
    int* galloc = gmeta + NBUCK;

    hipMemsetAsync(gmeta, 0, (size_t)(NBUCK + 1) * 4, stream);
    bucket_scatter2<<<ABLK, 256, 0, stream>>>(ei, gbcur, pairs);
    bucket_countplace<<<NBUCK, 256, 0, stream>>>(pairs, gbcur, galloc,
                                                 rowptr, rowend, dinv, ep);

    gemm1<<<(N + 128) / 128, 256, 0, stream>>>(x, W1, dinv, xw8);   // covers node N
    agg1<<<(N + 3) / 4, 256, 0, stream>>>(xw8, rowptr, rowend, ep, dinv, b1, hh);
    gemm2<<<(N + 128) / 128, 256, 0, stream>>>((const uint32*)hh, W2, dinv, xw2h);
    agg2<<<(N + 3) / 4, 256, 0, stream>>>((const uint32*)xw2h, rowptr, rowend, ep, dinv, b2, out);
}

// Round 13
// 264.458 us; speedup vs baseline: 1.0748x; 1.0748x over previous
//
#include <hip/hip_runtime.h>
#include <hip/hip_fp16.h>

// GCN 2-layer inference, N=100000, E=1600000, F_IN=100, H=128, C=47.
// R16 (base R14 266.6us + R15's fused CSR): (a) REVERT nontemporal loads
// (R15: FETCH unchanged, ep stream slower on the address chain -> +18us);
// (b) agg2 table -> row-scaled int8: 48 int8 + f32 scale in a 64B row
// = EXACTLY 1 cache line per edge (was 96B fp16 = 2 lines), table 9.6->6.4MB.
// Per-row scale keeps error ~rowmax/254 (~5-15x better than e4m3; R4's
// plain-fp8 layer2 failed at 0.0137). gemm2 epilogue: rowmax via 2x shfl_xor
// (octs of a node live in lanes m,m+16,m+32,m+48), quantize+pack; agg2:
// 16 lanes/edge x 4 edges/step, scale broadcast from q=12 lane via shfl.
// agg1/gemm1 = R14. Expect agg2 FETCH 110->~60MB, total ~248us, absmax ~0.0085.

typedef unsigned int uint32;
typedef float f32x2 __attribute__((ext_vector_type(2)));
typedef __fp16 fp16x2 __attribute__((ext_vector_type(2)));
typedef _Float16 h2v __attribute__((ext_vector_type(2)));
typedef _Float16 f16x8 __attribute__((ext_vector_type(8)));
typedef float f32x4 __attribute__((ext_vector_type(4)));

constexpr int N    = 100000;
constexpr int E    = 1600000;
constexpr int FIN  = 100;
constexpr int HD   = 128;
constexpr int C    = 47;
constexpr int EN_CAP = E + 8 * N;    // padded edge-slot upper bound

// bucketed CSR build
constexpr int NPB   = 512;                          // nodes per bucket (dst>>9)
constexpr int NBUCK = (N + NPB - 1) / NPB;          // 196
constexpr int ABLK  = 400;                          // scatter blocks
constexpr int EPB   = E / ABLK;                     // 4000 edges per block
constexpr int BCAP  = 16384;                        // bucket capacity

// ---------- fp8 / fp16 helpers ----------

__device__ __forceinline__ uint32 pack_fp8x4(float x, float y, float z, float w) {
    int r = __builtin_amdgcn_cvt_pk_fp8_f32(x, y, 0, false);   // bytes 0,1
    r = __builtin_amdgcn_cvt_pk_fp8_f32(z, w, r, true);        // bytes 2,3
    return (uint32)r;
}

__device__ __forceinline__ void acc_fp8x4(uint32 v, float& a0, float& a1,
                                          float& a2, float& a3) {
    f32x2 lo = __builtin_amdgcn_cvt_pk_f32_fp8((int)v, false);
    f32x2 hi = __builtin_amdgcn_cvt_pk_f32_fp8((int)v, true);
    a0 += lo[0]; a1 += lo[1]; a2 += hi[0]; a3 += hi[1];
}

__device__ __forceinline__ uint32 pk16(float a, float b) {
    union { fp16x2 h; uint32 u; } x;
    x.h = __builtin_amdgcn_cvt_pkrtz(a, b);    // v_cvt_pkrtz_f16_f32
    return x.u;
}

// ---------- CSR build: 2 kernels (+memset), no serial passes ----------

__global__ __launch_bounds__(256) void bucket_scatter2(const int* __restrict__ ei,
                                                       int* __restrict__ gbcur,
                                                       uint32* __restrict__ pairs) {
    __shared__ int h[NBUCK];
    __shared__ int baseL[NBUCK];
    __shared__ int cur[NBUCK];
    int t = threadIdx.x, blk = blockIdx.x;
    for (int i = t; i < NBUCK; i += 256) h[i] = 0;
    __syncthreads();
    int base = blk * EPB;
    for (int i = t; i < EPB; i += 256)
        atomicAdd(&h[ei[E + base + i] >> 9], 1);
    __syncthreads();
    for (int i = t; i < NBUCK; i += 256) {
        baseL[i] = i * BCAP + atomicAdd(&gbcur[i], h[i]);
        cur[i] = 0;
    }
    __syncthreads();
    for (int i = t; i < EPB; i += 256) {
        int s = ei[base + i];
        int d = ei[E + base + i];
        int b = d >> 9;
        int off = atomicAdd(&cur[b], 1);
        pairs[baseL[b] + off] = (uint32)s | ((uint32)(d & (NPB - 1)) << 20);
    }
}

// count + 512-entry cap-scan + atomic CSR-base alloc -> rowptr/rowend/dinv/
// self-loop/pads, THEN place edges (pairs L2-hot from the count phase).
__global__ __launch_bounds__(256) void bucket_countplace(const uint32* __restrict__ pairs,
                                                         const int* __restrict__ gbcur,
                                                         int* __restrict__ galloc,
                                                         int* __restrict__ rowptr,
                                                         int* __restrict__ rowend,
                                                         float* __restrict__ dinv,
                                                         int* __restrict__ ep) {
    __shared__ int c[NPB];     // degrees (kept through place phase)
    __shared__ int sm[NPB];    // inclusive cap-scan (kept)
    __shared__ int cur[NPB];   // place cursors
    __shared__ int sbase;
    int b = blockIdx.x, t = threadIdx.x;
    for (int i = t; i < NPB; i += 256) c[i] = 1;   // self loop
    __syncthreads();
    int pbase = b * BCAP;
    int blen = gbcur[b];
    for (int i = t; i < blen; i += 256)
        atomicAdd(&c[pairs[pbase + i] >> 20], 1);
    __syncthreads();
    int node0 = b * NPB;
    int i0 = t, i1 = t + 256;
    int n0 = node0 + i0, n1 = node0 + i1;
    int deg0 = (n0 < N) ? c[i0] : 0;
    int deg1 = (n1 < N) ? c[i1] : 0;
    int cap0 = (deg0 + 7) & ~7;     // 0 stays 0 for invalid nodes
    int cap1 = (deg1 + 7) & ~7;
    sm[i0] = cap0; sm[i1] = cap1;
    __syncthreads();
    for (int off = 1; off < NPB; off <<= 1) {
        int o0 = sm[i0], o1 = sm[i1];
        int a0 = (i0 >= off) ? sm[i0 - off] : 0;
        int a1 = (i1 >= off) ? sm[i1 - off] : 0;
        __syncthreads();
        sm[i0] = o0 + a0; sm[i1] = o1 + a1;
        __syncthreads();
    }
    if (t == 0) sbase = atomicAdd(galloc, sm[NPB - 1]);
    __syncthreads();
    int gb = sbase;
    if (n0 < N) {
        int beg = gb + sm[i0] - cap0;
        rowptr[n0] = beg; rowend[n0] = beg + cap0;
        dinv[n0] = rsqrtf((float)deg0);
        ep[beg] = n0;                                  // self loop at slot 0
        for (int k = deg0; k < cap0; ++k) ep[beg + k] = N;  // pads -> zero row
    }
    if (n1 < N) {
        int beg = gb + sm[i1] - cap1;
        rowptr[n1] = beg; rowend[n1] = beg + cap1;
        dinv[n1] = rsqrtf((float)deg1);
        ep[beg] = n1;
        for (int k = deg1; k < cap1; ++k) ep[beg + k] = N;
    }
    // place phase: cursors start at 1 (slot 0 = self loop)
    cur[i0] = 1; cur[i1] = 1;
    __syncthreads();
    for (int i = t; i < blen; i += 256) {
        uint32 p = pairs[pbase + i];
        int dl = p >> 20;
        int slot = atomicAdd(&cur[dl], 1);
        int rowbeg = gb + sm[dl] - ((c[dl] + 7) & ~7);
        ep[rowbeg + slot] = (int)(p & 0xFFFFF);
    }
}

// ---------- GEMM1 (MFMA): xw8[N+1,32 dwords] fp8 = dinv[n]*(x @ W1) ----------

__global__ __launch_bounds__(256) void gemm1(const float* __restrict__ x,
                                             const float* __restrict__ W1,
                                             const float* __restrict__ dinv,
                                             uint32* __restrict__ xw8) {
    __shared__ uint32 sA[8192];   // 32 KB, frag-linear: [(nt*4+ks)*256 + l*4 + d]
    int tx = threadIdx.x;

    for (int idx = tx; idx < 8192; idx += 256) {
        int slot = idx >> 8;               // nt*4 + ks
        int rem  = idx & 255;
        int l = rem >> 2, d = rem & 3;
        int nt = slot >> 2, ks = slot & 3;
        int n = nt * 16 + (l & 15);
        int k = ks * 32 + (l >> 4) * 8 + 2 * d;
        float va = (k < FIN)     ? W1[k * HD + n]       : 0.f;
        float vb = (k + 1 < FIN) ? W1[(k + 1) * HD + n] : 0.f;
        sA[idx] = pk16(va, vb);
    }
    __syncthreads();

    int l = tx & 63, w = tx >> 6;
    int m = l & 15, oct = l >> 4;
    size_t node0 = (size_t)blockIdx.x * 128 + (size_t)w * 32;
    size_t nA = node0 + m;          // node-tile 0
    size_t nB = node0 + 16 + m;     // node-tile 1

    f32x4 acc0[8], acc1[8];
#pragma unroll
    for (int nt = 0; nt < 8; ++nt) {
        acc0[nt] = (f32x4){0.f, 0.f, 0.f, 0.f};
        acc1[nt] = (f32x4){0.f, 0.f, 0.f, 0.f};
    }

#pragma unroll
    for (int ks = 0; ks < 4; ++ks) {
        int k0 = ks * 32 + oct * 8;
        float4 fa0 = make_float4(0.f, 0.f, 0.f, 0.f), fa1 = fa0;
        float4 fb0 = make_float4(0.f, 0.f, 0.f, 0.f), fb1 = fb0;
        if (nA < (size_t)N) {
            const float* xr = x + nA * FIN;
            if (k0 < FIN)     fa0 = *(const float4*)(xr + k0);
            if (k0 + 4 < FIN) fa1 = *(const float4*)(xr + k0 + 4);
        }
        if (nB < (size_t)N) {
            const float* xr = x + nB * FIN;
            if (k0 < FIN)     fb0 = *(const float4*)(xr + k0);
            if (k0 + 4 < FIN) fb1 = *(const float4*)(xr + k0 + 4);
        }
        union { uint4 u; f16x8 h; } b0, b1;
        b0.u = make_uint4(pk16(fa0.x, fa0.y), pk16(fa0.z, fa0.w),
                          pk16(fa1.x, fa1.y), pk16(fa1.z, fa1.w));
        b1.u = make_uint4(pk16(fb0.x, fb0.y), pk16(fb0.z, fb0.w),
                          pk16(fb1.x, fb1.y), pk16(fb1.z, fb1.w));
#pragma unroll
        for (int nt = 0; nt < 8; ++nt) {
            union { uint4 u; f16x8 h; } a;
            a.u = *(const uint4*)&sA[(nt * 4 + ks) * 256 + l * 4];
            acc0[nt] = __builtin_amdgcn_mfma_f32_16x16x32_f16(a.h, b0.h, acc0[nt], 0, 0, 0);
            acc1[nt] = __builtin_amdgcn_mfma_f32_16x16x32_f16(a.h, b1.h, acc1[nt], 0, 0, 0);
        }
    }

    if (nA <= (size_t)N) {
        float dv = (nA < (size_t)N) ? dinv[nA] : 0.f;
#pragma unroll
        for (int nt = 0; nt < 8; ++nt) {
            f32x4 v = acc0[nt];
            uint32 p = (nA < (size_t)N)
                ? pack_fp8x4(v[0] * dv, v[1] * dv, v[2] * dv, v[3] * dv) : 0u;
            xw8[nA * 32 + nt * 4 + oct] = p;
        }
    }
    if (nB <= (size_t)N) {
        float dv = (nB < (size_t)N) ? dinv[nB] : 0.f;
#pragma unroll
        for (int nt = 0; nt < 8; ++nt) {
            f32x4 v = acc1[nt];
            uint32 p = (nB < (size_t)N)
                ? pack_fp8x4(v[0] * dv, v[1] * dv, v[2] * dv, v[3] * dv) : 0u;
            xw8[nB * 32 + nt * 4 + oct] = p;
        }
    }
}

// ---------- agg1: h[n] (fp16) = relu(b1 + dinv[n] * sum_j xw8[src_j]) ----------
// R14 structure: 16-edge unroll (8 gather loads in flight), 8-edge tail.

__global__ __launch_bounds__(256) void agg1(const uint32* __restrict__ xw8,
                                            const int* __restrict__ rowptr,
                                            const int* __restrict__ rowend,
                                            const int* __restrict__ ep,
                                            const float* __restrict__ dinv,
                                            const float* __restrict__ b1,
                                            __half* __restrict__ h) {
    int node = blockIdx.x * 4 + (threadIdx.x >> 6);
    if (node >= N) return;
    int lane = threadIdx.x & 63;
    int hf = lane >> 5;      // which edge of the pair
    int q  = lane & 31;      // dword within 128B row -> dims q*4..q*4+3
    int beg = rowptr[node], end = rowend[node];   // cap, multiple of 8
    float a0 = 0.f, a1 = 0.f, a2 = 0.f, a3 = 0.f;
    int j = beg;
    for (; j + 16 <= end; j += 16) {
        int s0 = ep[j + hf];
        int s1 = ep[j + 2 + hf];
        int s2 = ep[j + 4 + hf];
        int s3 = ep[j + 6 + hf];
        int s4 = ep[j + 8 + hf];
        int s5 = ep[j + 10 + hf];
        int s6 = ep[j + 12 + hf];
        int s7 = ep[j + 14 + hf];
        uint32 v0 = xw8[(size_t)s0 * 32 + q];
        uint32 v1 = xw8[(size_t)s1 * 32 + q];
        uint32 v2 = xw8[(size_t)s2 * 32 + q];
        uint32 v3 = xw8[(size_t)s3 * 32 + q];
        uint32 v4 = xw8[(size_t)s4 * 32 + q];
        uint32 v5 = xw8[(size_t)s5 * 32 + q];
        uint32 v6 = xw8[(size_t)s6 * 32 + q];
        uint32 v7 = xw8[(size_t)s7 * 32 + q];
        acc_fp8x4(v0, a0, a1, a2, a3);
        acc_fp8x4(v1, a0, a1, a2, a3);
        acc_fp8x4(v2, a0, a1, a2, a3);
        acc_fp8x4(v3, a0, a1, a2, a3);
        acc_fp8x4(v4, a0, a1, a2, a3);
        acc_fp8x4(v5, a0, a1, a2, a3);
        acc_fp8x4(v6, a0, a1, a2, a3);
        acc_fp8x4(v7, a0, a1, a2, a3);
    }
    if (j < end) {   // 8 remaining
        int s0 = ep[j + hf];
        int s1 = ep[j + 2 + hf];
        int s2 = ep[j + 4 + hf];
        int s3 = ep[j + 6 + hf];
        uint32 v0 = xw8[(size_t)s0 * 32 + q];
        uint32 v1 = xw8[(size_t)s1 * 32 + q];
        uint32 v2 = xw8[(size_t)s2 * 32 + q];
        uint32 v3 = xw8[(size_t)s3 * 32 + q];
        acc_fp8x4(v0, a0, a1, a2, a3);
        acc_fp8x4(v1, a0, a1, a2, a3);
        acc_fp8x4(v2, a0, a1, a2, a3);
        acc_fp8x4(v3, a0, a1, a2, a3);
    }
    a0 += __shfl_xor(a0, 32);
    a1 += __shfl_xor(a1, 32);
    a2 += __shfl_xor(a2, 32);
    a3 += __shfl_xor(a3, 32);
    if (hf == 0) {
        float dv = dinv[node];
        float4 bb = *(const float4*)&b1[q * 4];
        float r0 = fmaxf(fmaf(dv, a0, bb.x), 0.f);
        float r1 = fmaxf(fmaf(dv, a1, bb.y), 0.f);
        float r2 = fmaxf(fmaf(dv, a2, bb.z), 0.f);
        float r3 = fmaxf(fmaf(dv, a3, bb.w), 0.f);
        union { __half2 h2[2]; uint2 u; } p;
        p.h2[0] = __floats2half2_rn(r0, r1);
        p.h2[1] = __floats2half2_rn(r2, r3);
        *(uint2*)&h[(size_t)node * HD + q * 4] = p.u;
    }
}

// ---------- GEMM2 (MFMA): xw2q[N+1,16 dwords] row-scaled int8 ----------
// Row: dwords 0-11 = 48 int8 cols, dword 12 = f32 scale, 13-15 pad. 64B/row.
// Rowmax over a node's 4 oct-lanes (m, m+16, m+32, m+48) via shfl_xor 16/32.

__global__ __launch_bounds__(256) void gemm2(const uint32* __restrict__ hh,
                                             const float* __restrict__ W2,
                                             const float* __restrict__ dinv,
                                             uint32* __restrict__ xw2q) {
    __shared__ uint32 sA[3072];   // 12 KB: [(nt*4+ks)*256 + l*4 + d]
    int tx = threadIdx.x;

    for (int idx = tx; idx < 3072; idx += 256) {
        int slot = idx >> 8;               // nt*4 + ks
        int rem  = idx & 255;
        int l = rem >> 2, d = rem & 3;
        int nt = slot >> 2, ks = slot & 3;
        int c = nt * 16 + (l & 15);
        int k = ks * 32 + (l >> 4) * 8 + 2 * d;
        float va = (c < C) ? W2[k * C + c]       : 0.f;
        float vb = (c < C) ? W2[(k + 1) * C + c] : 0.f;
        sA[idx] = pk16(va, vb);
    }
    __syncthreads();

    int l = tx & 63, w = tx >> 6;
    int m = l & 15, oct = l >> 4;
    size_t node0 = (size_t)blockIdx.x * 128 + (size_t)w * 32;
    size_t nA = node0 + m;
    size_t nB = node0 + 16 + m;

    f32x4 acc0[3], acc1[3];
#pragma unroll
    for (int nt = 0; nt < 3; ++nt) {
        acc0[nt] = (f32x4){0.f, 0.f, 0.f, 0.f};
        acc1[nt] = (f32x4){0.f, 0.f, 0.f, 0.f};
    }

#pragma unroll
    for (int ks = 0; ks < 4; ++ks) {
        union { uint4 u; f16x8 h; } b0, b1;
        b0.u = (nA < (size_t)N) ? *(const uint4*)&hh[nA * 64 + ks * 16 + oct * 4]
                                : make_uint4(0u, 0u, 0u, 0u);
        b1.u = (nB < (size_t)N) ? *(const uint4*)&hh[nB * 64 + ks * 16 + oct * 4]
                                : make_uint4(0u, 0u, 0u, 0u);
#pragma unroll
        for (int nt = 0; nt < 3; ++nt) {
            union { uint4 u; f16x8 h; } a;
            a.u = *(const uint4*)&sA[(nt * 4 + ks) * 256 + l * 4];
            acc0[nt] = __builtin_amdgcn_mfma_f32_16x16x32_f16(a.h, b0.h, acc0[nt], 0, 0, 0);
            acc1[nt] = __builtin_amdgcn_mfma_f32_16x16x32_f16(a.h, b1.h, acc1[nt], 0, 0, 0);
        }
    }

    // scale accumulators by dinv, find rowmax across octs, quantize int8
    float vA[12], vB[12];
    float dvA = (nA < (size_t)N) ? dinv[nA] : 0.f;
    float dvB = (nB < (size_t)N) ? dinv[nB] : 0.f;
    float mxA = 0.f, mxB = 0.f;
#pragma unroll
    for (int nt = 0; nt < 3; ++nt) {
#pragma unroll
        for (int i = 0; i < 4; ++i) {
            float a = acc0[nt][i] * dvA;
            float b = acc1[nt][i] * dvB;
            vA[nt * 4 + i] = a; vB[nt * 4 + i] = b;
            mxA = fmaxf(mxA, fabsf(a));
            mxB = fmaxf(mxB, fabsf(b));
        }
    }
    mxA = fmaxf(mxA, __shfl_xor(mxA, 16)); mxA = fmaxf(mxA, __shfl_xor(mxA, 32));
    mxB = fmaxf(mxB, __shfl_xor(mxB, 16)); mxB = fmaxf(mxB, __shfl_xor(mxB, 32));
    float scA = mxA * (1.f / 127.f), invA = (mxA > 0.f) ? 127.f / mxA : 0.f;
    float scB = mxB * (1.f / 127.f), invB = (mxB > 0.f) ? 127.f / mxB : 0.f;

    if (nA <= (size_t)N) {
#pragma unroll
        for (int nt = 0; nt < 3; ++nt) {
            uint32 p = 0;
#pragma unroll
            for (int i = 0; i < 4; ++i) {
                int qv = __float2int_rn(vA[nt * 4 + i] * invA);
                p |= ((uint32)qv & 255u) << (8 * i);
            }
            xw2q[nA * 16 + nt * 4 + oct] = p;
        }
        if (oct == 0) xw2q[nA * 16 + 12] = __float_as_uint(scA);
    }
    if (nB <= (size_t)N) {
#pragma unroll
        for (int nt = 0; nt < 3; ++nt) {
            uint32 p = 0;
#pragma unroll
            for (int i = 0; i < 4; ++i) {
                int qv = __float2int_rn(vB[nt * 4 + i] * invB);
                p |= ((uint32)qv & 255u) << (8 * i);
            }
            xw2q[nB * 16 + nt * 4 + oct] = p;
        }
        if (oct == 0) xw2q[nB * 16 + 12] = __float_as_uint(scB);
    }
}

// ---------- agg2: out[n] = b2 + dinv[n] * sum_j dequant(xw2q[src_j]) ----------
// 16 lanes per edge (64B row = 1 line), 4 edges/step, 16-edge unroll + 8 tail.
// Scale broadcast from the q=12 lane of each edge group via shfl.

__global__ __launch_bounds__(256) void agg2(const uint32* __restrict__ xw2q,
                                            const int* __restrict__ rowptr,
                                            const int* __restrict__ rowend,
                                            const int* __restrict__ ep,
                                            const float* __restrict__ dinv,
                                            const float* __restrict__ b2,
                                            float* __restrict__ out) {
    int node = blockIdx.x * 4 + (threadIdx.x >> 6);
    if (node >= N) return;
    int lane = threadIdx.x & 63;
    int g = lane >> 4;       // edge group 0..3
    int q = lane & 15;       // dword within 64B row
    int sl = (lane & 48) | 12;   // lane holding the scale dword of this group
    int beg = rowptr[node], end = rowend[node];   // cap, multiple of 8
    float a0 = 0.f, a1 = 0.f, a2 = 0.f, a3 = 0.f;
    int j = beg;
    for (; j + 16 <= end; j += 16) {
        int s0 = ep[j + g];
        int s1 = ep[j + 4 + g];
        int s2 = ep[j + 8 + g];
        int s3 = ep[j + 12 + g];
        uint32 v0 = xw2q[(size_t)s0 * 16 + q];
        uint32 v1 = xw2q[(size_t)s1 * 16 + q];
        uint32 v2 = xw2q[(size_t)s2 * 16 + q];
        uint32 v3 = xw2q[(size_t)s3 * 16 + q];
        float c0 = __uint_as_float(__shfl((int)v0, sl));
        float c1 = __uint_as_float(__shfl((int)v1, sl));
        float c2 = __uint_as_float(__shfl((int)v2, sl));
        float c3 = __uint_as_float(__shfl((int)v3, sl));
        a0 = fmaf(c0, (float)((int)(v0 << 24) >> 24), a0);
        a1 = fmaf(c0, (float)((int)(v0 << 16) >> 24), a1);
        a2 = fmaf(c0, (float)((int)(v0 <<  8) >> 24), a2);
        a3 = fmaf(c0, (float)((int)v0 >> 24),         a3);
        a0 = fmaf(c1, (float)((int)(v1 << 24) >> 24), a0);
        a1 = fmaf(c1, (float)((int)(v1 << 16) >> 24), a1);
        a2 = fmaf(c1, (float)((int)(v1 <<  8) >> 24), a2);
        a3 = fmaf(c1, (float)((int)v1 >> 24),         a3);
        a0 = fmaf(c2, (float)((int)(v2 << 24) >> 24), a0);
        a1 = fmaf(c2, (float)((int)(v2 << 16) >> 24), a1);
        a2 = fmaf(c2, (float)((int)(v2 <<  8) >> 24), a2);
        a3 = fmaf(c2, (float)((int)v2 >> 24),         a3);
        a0 = fmaf(c3, (float)((int)(v3 << 24) >> 24), a0);
        a1 = fmaf(c3, (float)((int)(v3 << 16) >> 24), a1);
        a2 = fmaf(c3, (float)((int)(v3 <<  8) >> 24), a2);
        a3 = fmaf(c3, (float)((int)v3 >> 24),         a3);
    }
    if (j < end) {   // 8 remaining
        int s0 = ep[j + g];
        int s1 = ep[j + 4 + g];
        uint32 v0 = xw2q[(size_t)s0 * 16 + q];
        uint32 v1 = xw2q[(size_t)s1 * 16 + q];
        float c0 = __uint_as_float(__shfl((int)v0, sl));
        float c1 = __uint_as_float(__shfl((int)v1, sl));
        a0 = fmaf(c0, (float)((int)(v0 << 24) >> 24), a0);
        a1 = fmaf(c0, (float)((int)(v0 << 16) >> 24), a1);
        a2 = fmaf(c0, (float)((int)(v0 <<  8) >> 24), a2);
        a3 = fmaf(c0, (float)((int)v0 >> 24),         a3);
        a0 = fmaf(c1, (float)((int)(v1 << 24) >> 24), a0);
        a1 = fmaf(c1, (float)((int)(v1 << 16) >> 24), a1);
        a2 = fmaf(c1, (float)((int)(v1 <<  8) >> 24), a2);
        a3 = fmaf(c1, (float)((int)v1 >> 24),         a3);
    }
    // combine the 4 edge groups (bits 4-5 of lane)
    a0 += __shfl_xor(a0, 16); a0 += __shfl_xor(a0, 32);
    a1 += __shfl_xor(a1, 16); a1 += __shfl_xor(a1, 32);
    a2 += __shfl_xor(a2, 16); a2 += __shfl_xor(a2, 32);
    a3 += __shfl_xor(a3, 16); a3 += __shfl_xor(a3, 32);
    if (g == 0 && q < 12) {
        float dv = dinv[node];
        int c = q * 4;
        out[(size_t)node * C + c]     = fmaf(dv, a0, b2[c]);
        out[(size_t)node * C + c + 1] = fmaf(dv, a1, b2[c + 1]);
        out[(size_t)node * C + c + 2] = fmaf(dv, a2, b2[c + 2]);
        if (c + 3 < C)
            out[(size_t)node * C + c + 3] = fmaf(dv, a3, b2[c + 3]);
    }
}

extern "C" void kernel_launch(void* const* d_in, const int* in_sizes, int n_in,
                              void* d_out, int out_size, void* d_ws, size_t ws_size,
                              hipStream_t stream) {
    const float* x  = (const float*)d_in[0];
    const int*   ei = (const int*)d_in[1];
    const float* W1 = (const float*)d_in[2];
    const float* b1 = (const float*)d_in[3];
    const float* W2 = (const float*)d_in[4];
    const float* b2 = (const float*)d_in[5];
    float* out = (float*)d_out;

    size_t off = 0;
    auto alloc = [&](size_t bytes) {
        void* p = (char*)d_ws + off;
        off += (bytes + 255) & ~(size_t)255;
        return p;
    };
    int*    gmeta   = (int*)alloc((size_t)(NBUCK + 64) * 4);  // gbcur[NBUCK] + galloc
    uint32* pairs   = (uint32*)alloc((size_t)NBUCK * BCAP * 4);   // 12.8 MB
    int*    rowptr  = (int*)alloc((size_t)N * 4);
    int*    rowend  = (int*)alloc((size_t)N * 4);
    float*  dinv    = (float*)alloc((size_t)N * 4);
    int*    ep      = (int*)alloc((size_t)EN_CAP * 4);
    uint32* xw8     = (uint32*)alloc((size_t)(N + 1) * 32 * 4);   // fp8 [N+1][128]
    __half* hh      = (__half*)alloc((size_t)N * HD * 2);
    uint32* xw2q    = (uint32*)alloc((size_t)(N + 1) * 16 * 4);   // int8+scale [N+1][64B]
    (void)ws_size;
    int* gbcur  = gmeta;
    int* galloc = gmeta + NBUCK;

    hipMemsetAsync(gmeta, 0, (size_t)(NBUCK + 1) * 4, stream);
    bucket_scatter2<<<ABLK, 256, 0, stream>>>(ei, gbcur, pairs);
    bucket_countplace<<<NBUCK, 256, 0, stream>>>(pairs, gbcur, galloc,
                                                 rowptr, rowend, dinv, ep);

    gemm1<<<(N + 128) / 128, 256, 0, stream>>>(x, W1, dinv, xw8);   // covers node N
    agg1<<<(N + 3) / 4, 256, 0, stream>>>(xw8, rowptr, rowend, ep, dinv, b1, hh);
    gemm2<<<(N + 128) / 128, 256, 0, stream>>>((const uint32*)hh, W2, dinv, xw2q);
    agg2<<<(N + 3) / 4, 256, 0, stream>>>(xw2q, rowptr, rowend, ep, dinv, b2, out);
}

// Round 14
// 251.694 us; speedup vs baseline: 1.1293x; 1.0507x over previous
//
#include <hip/hip_runtime.h>
#include <hip/hip_fp16.h>

// GCN 2-layer inference, N=100000, E=1600000, F_IN=100, H=128, C=47.
// R17 (base R16, 264.5us): remove per-block LDS fragment staging from both
// GEMMs. R16 profile: gemm1 top at 44.8us with MfmaUtil 2.5%, VALU 8.6%,
// occ 19% -> the 32KB W1 frag table was rebuilt by EVERY block with 64
// strided scalar loads/thread + barrier (latency-bound prologue). New:
// prep_frags (44 blocks, one slot/thread) writes w1frag (32KB) and w2frag
// (12KB) in MFMA fragment order to GLOBAL once; gemms read A-frags directly
// (lane l -> frag[base+l*4], 1KB/wave contiguous, L2-resident broadcast).
// No LDS, no barrier in gemms; occupancy VGPR-limited only.
// CSR (fused atomic-alloc), agg1 (fp8), agg2 (row-scaled int8) = R16.

typedef unsigned int uint32;
typedef float f32x2 __attribute__((ext_vector_type(2)));
typedef __fp16 fp16x2 __attribute__((ext_vector_type(2)));
typedef _Float16 f16x8 __attribute__((ext_vector_type(8)));
typedef float f32x4 __attribute__((ext_vector_type(4)));

constexpr int N    = 100000;
constexpr int E    = 1600000;
constexpr int FIN  = 100;
constexpr int HD   = 128;
constexpr int C    = 47;
constexpr int EN_CAP = E + 8 * N;    // padded edge-slot upper bound

// bucketed CSR build
constexpr int NPB   = 512;                          // nodes per bucket (dst>>9)
constexpr int NBUCK = (N + NPB - 1) / NPB;          // 196
constexpr int ABLK  = 400;                          // scatter blocks
constexpr int EPB   = E / ABLK;                     // 4000 edges per block
constexpr int BCAP  = 16384;                        // bucket capacity

constexpr int W1F = 8192;   // w1frag dwords (32 KB)
constexpr int W2F = 3072;   // w2frag dwords (12 KB)

// ---------- fp8 / fp16 helpers ----------

__device__ __forceinline__ uint32 pack_fp8x4(float x, float y, float z, float w) {
    int r = __builtin_amdgcn_cvt_pk_fp8_f32(x, y, 0, false);   // bytes 0,1
    r = __builtin_amdgcn_cvt_pk_fp8_f32(z, w, r, true);        // bytes 2,3
    return (uint32)r;
}

__device__ __forceinline__ void acc_fp8x4(uint32 v, float& a0, float& a1,
                                          float& a2, float& a3) {
    f32x2 lo = __builtin_amdgcn_cvt_pk_f32_fp8((int)v, false);
    f32x2 hi = __builtin_amdgcn_cvt_pk_f32_fp8((int)v, true);
    a0 += lo[0]; a1 += lo[1]; a2 += hi[0]; a3 += hi[1];
}

__device__ __forceinline__ uint32 pk16(float a, float b) {
    union { fp16x2 h; uint32 u; } x;
    x.h = __builtin_amdgcn_cvt_pkrtz(a, b);    // v_cvt_pkrtz_f16_f32
    return x.u;
}

// ---------- prep: W1/W2 -> fp16 fragment tables (once, global) ----------
// slot layout [(nt*4+ks)*256 + l*4 + d]: lane l, dword d holds
// pk16(W[k][col], W[k+1][col]) with k = ks*32+(l>>4)*8+2d, col = nt*16+(l&15).

__global__ void prep_frags(const float* __restrict__ W1, const float* __restrict__ W2,
                           uint32* __restrict__ w1f, uint32* __restrict__ w2f) {
    int idx = blockIdx.x * 256 + threadIdx.x;
    if (idx < W1F) {
        int slot = idx >> 8, rem = idx & 255;
        int l = rem >> 2, d = rem & 3;
        int nt = slot >> 2, ks = slot & 3;
        int n = nt * 16 + (l & 15);
        int k = ks * 32 + (l >> 4) * 8 + 2 * d;
        float va = (k < FIN)     ? W1[k * HD + n]       : 0.f;
        float vb = (k + 1 < FIN) ? W1[(k + 1) * HD + n] : 0.f;
        w1f[idx] = pk16(va, vb);
    } else if (idx < W1F + W2F) {
        int j = idx - W1F;
        int slot = j >> 8, rem = j & 255;
        int l = rem >> 2, d = rem & 3;
        int nt = slot >> 2, ks = slot & 3;
        int c = nt * 16 + (l & 15);
        int k = ks * 32 + (l >> 4) * 8 + 2 * d;
        float va = (c < C) ? W2[k * C + c]       : 0.f;
        float vb = (c < C) ? W2[(k + 1) * C + c] : 0.f;
        w2f[j] = pk16(va, vb);
    }
}

// ---------- CSR build: 2 kernels (+memset), no serial passes ----------

__global__ __launch_bounds__(256) void bucket_scatter2(const int* __restrict__ ei,
                                                       int* __restrict__ gbcur,
                                                       uint32* __restrict__ pairs) {
    __shared__ int h[NBUCK];
    __shared__ int baseL[NBUCK];
    __shared__ int cur[NBUCK];
    int t = threadIdx.x, blk = blockIdx.x;
    for (int i = t; i < NBUCK; i += 256) h[i] = 0;
    __syncthreads();
    int base = blk * EPB;
    for (int i = t; i < EPB; i += 256)
        atomicAdd(&h[ei[E + base + i] >> 9], 1);
    __syncthreads();
    for (int i = t; i < NBUCK; i += 256) {
        baseL[i] = i * BCAP + atomicAdd(&gbcur[i], h[i]);
        cur[i] = 0;
    }
    __syncthreads();
    for (int i = t; i < EPB; i += 256) {
        int s = ei[base + i];
        int d = ei[E + base + i];
        int b = d >> 9;
        int off = atomicAdd(&cur[b], 1);
        pairs[baseL[b] + off] = (uint32)s | ((uint32)(d & (NPB - 1)) << 20);
    }
}

// count + 512-entry cap-scan + atomic CSR-base alloc -> rowptr/rowend/dinv/
// self-loop/pads, THEN place edges (pairs L2-hot from the count phase).
__global__ __launch_bounds__(256) void bucket_countplace(const uint32* __restrict__ pairs,
                                                         const int* __restrict__ gbcur,
                                                         int* __restrict__ galloc,
                                                         int* __restrict__ rowptr,
                                                         int* __restrict__ rowend,
                                                         float* __restrict__ dinv,
                                                         int* __restrict__ ep) {
    __shared__ int c[NPB];     // degrees (kept through place phase)
    __shared__ int sm[NPB];    // inclusive cap-scan (kept)
    __shared__ int cur[NPB];   // place cursors
    __shared__ int sbase;
    int b = blockIdx.x, t = threadIdx.x;
    for (int i = t; i < NPB; i += 256) c[i] = 1;   // self loop
    __syncthreads();
    int pbase = b * BCAP;
    int blen = gbcur[b];
    for (int i = t; i < blen; i += 256)
        atomicAdd(&c[pairs[pbase + i] >> 20], 1);
    __syncthreads();
    int node0 = b * NPB;
    int i0 = t, i1 = t + 256;
    int n0 = node0 + i0, n1 = node0 + i1;
    int deg0 = (n0 < N) ? c[i0] : 0;
    int deg1 = (n1 < N) ? c[i1] : 0;
    int cap0 = (deg0 + 7) & ~7;     // 0 stays 0 for invalid nodes
    int cap1 = (deg1 + 7) & ~7;
    sm[i0] = cap0; sm[i1] = cap1;
    __syncthreads();
    for (int off = 1; off < NPB; off <<= 1) {
        int o0 = sm[i0], o1 = sm[i1];
        int a0 = (i0 >= off) ? sm[i0 - off] : 0;
        int a1 = (i1 >= off) ? sm[i1 - off] : 0;
        __syncthreads();
        sm[i0] = o0 + a0; sm[i1] = o1 + a1;
        __syncthreads();
    }
    if (t == 0) sbase = atomicAdd(galloc, sm[NPB - 1]);
    __syncthreads();
    int gb = sbase;
    if (n0 < N) {
        int beg = gb + sm[i0] - cap0;
        rowptr[n0] = beg; rowend[n0] = beg + cap0;
        dinv[n0] = rsqrtf((float)deg0);
        ep[beg] = n0;                                  // self loop at slot 0
        for (int k = deg0; k < cap0; ++k) ep[beg + k] = N;  // pads -> zero row
    }
    if (n1 < N) {
        int beg = gb + sm[i1] - cap1;
        rowptr[n1] = beg; rowend[n1] = beg + cap1;
        dinv[n1] = rsqrtf((float)deg1);
        ep[beg] = n1;
        for (int k = deg1; k < cap1; ++k) ep[beg + k] = N;
    }
    // place phase: cursors start at 1 (slot 0 = self loop)
    cur[i0] = 1; cur[i1] = 1;
    __syncthreads();
    for (int i = t; i < blen; i += 256) {
        uint32 p = pairs[pbase + i];
        int dl = p >> 20;
        int slot = atomicAdd(&cur[dl], 1);
        int rowbeg = gb + sm[dl] - ((c[dl] + 7) & ~7);
        ep[rowbeg + slot] = (int)(p & 0xFFFFF);
    }
}

// ---------- GEMM1 (MFMA, no LDS): xw8[N+1,32 dwords] fp8 = dinv[n]*(x @ W1) ----------

__global__ __launch_bounds__(256) void gemm1(const float* __restrict__ x,
                                             const uint32* __restrict__ w1f,
                                             const float* __restrict__ dinv,
                                             uint32* __restrict__ xw8) {
    int tx = threadIdx.x;
    int l = tx & 63, w = tx >> 6;
    int m = l & 15, oct = l >> 4;
    size_t node0 = (size_t)blockIdx.x * 128 + (size_t)w * 32;
    size_t nA = node0 + m;          // node-tile 0
    size_t nB = node0 + 16 + m;     // node-tile 1

    f32x4 acc0[8], acc1[8];
#pragma unroll
    for (int nt = 0; nt < 8; ++nt) {
        acc0[nt] = (f32x4){0.f, 0.f, 0.f, 0.f};
        acc1[nt] = (f32x4){0.f, 0.f, 0.f, 0.f};
    }

#pragma unroll
    for (int ks = 0; ks < 4; ++ks) {
        int k0 = ks * 32 + oct * 8;
        float4 fa0 = make_float4(0.f, 0.f, 0.f, 0.f), fa1 = fa0;
        float4 fb0 = make_float4(0.f, 0.f, 0.f, 0.f), fb1 = fb0;
        if (nA < (size_t)N) {
            const float* xr = x + nA * FIN;
            if (k0 < FIN)     fa0 = *(const float4*)(xr + k0);
            if (k0 + 4 < FIN) fa1 = *(const float4*)(xr + k0 + 4);
        }
        if (nB < (size_t)N) {
            const float* xr = x + nB * FIN;
            if (k0 < FIN)     fb0 = *(const float4*)(xr + k0);
            if (k0 + 4 < FIN) fb1 = *(const float4*)(xr + k0 + 4);
        }
        union { uint4 u; f16x8 h; } b0, b1;
        b0.u = make_uint4(pk16(fa0.x, fa0.y), pk16(fa0.z, fa0.w),
                          pk16(fa1.x, fa1.y), pk16(fa1.z, fa1.w));
        b1.u = make_uint4(pk16(fb0.x, fb0.y), pk16(fb0.z, fb0.w),
                          pk16(fb1.x, fb1.y), pk16(fb1.z, fb1.w));
#pragma unroll
        for (int nt = 0; nt < 8; ++nt) {
            union { uint4 u; f16x8 h; } a;
            a.u = *(const uint4*)&w1f[(nt * 4 + ks) * 256 + l * 4];
            acc0[nt] = __builtin_amdgcn_mfma_f32_16x16x32_f16(a.h, b0.h, acc0[nt], 0, 0, 0);
            acc1[nt] = __builtin_amdgcn_mfma_f32_16x16x32_f16(a.h, b1.h, acc1[nt], 0, 0, 0);
        }
    }

    if (nA <= (size_t)N) {
        float dv = (nA < (size_t)N) ? dinv[nA] : 0.f;
#pragma unroll
        for (int nt = 0; nt < 8; ++nt) {
            f32x4 v = acc0[nt];
            uint32 p = (nA < (size_t)N)
                ? pack_fp8x4(v[0] * dv, v[1] * dv, v[2] * dv, v[3] * dv) : 0u;
            xw8[nA * 32 + nt * 4 + oct] = p;
        }
    }
    if (nB <= (size_t)N) {
        float dv = (nB < (size_t)N) ? dinv[nB] : 0.f;
#pragma unroll
        for (int nt = 0; nt < 8; ++nt) {
            f32x4 v = acc1[nt];
            uint32 p = (nB < (size_t)N)
                ? pack_fp8x4(v[0] * dv, v[1] * dv, v[2] * dv, v[3] * dv) : 0u;
            xw8[nB * 32 + nt * 4 + oct] = p;
        }
    }
}

// ---------- agg1: h[n] (fp16) = relu(b1 + dinv[n] * sum_j xw8[src_j]) ----------
// 16-edge unroll (8 gather loads in flight), 8-edge tail.

__global__ __launch_bounds__(256) void agg1(const uint32* __restrict__ xw8,
                                            const int* __restrict__ rowptr,
                                            const int* __restrict__ rowend,
                                            const int* __restrict__ ep,
                                            const float* __restrict__ dinv,
                                            const float* __restrict__ b1,
                                            __half* __restrict__ h) {
    int node = blockIdx.x * 4 + (threadIdx.x >> 6);
    if (node >= N) return;
    int lane = threadIdx.x & 63;
    int hf = lane >> 5;      // which edge of the pair
    int q  = lane & 31;      // dword within 128B row -> dims q*4..q*4+3
    int beg = rowptr[node], end = rowend[node];   // cap, multiple of 8
    float a0 = 0.f, a1 = 0.f, a2 = 0.f, a3 = 0.f;
    int j = beg;
    for (; j + 16 <= end; j += 16) {
        int s0 = ep[j + hf];
        int s1 = ep[j + 2 + hf];
        int s2 = ep[j + 4 + hf];
        int s3 = ep[j + 6 + hf];
        int s4 = ep[j + 8 + hf];
        int s5 = ep[j + 10 + hf];
        int s6 = ep[j + 12 + hf];
        int s7 = ep[j + 14 + hf];
        uint32 v0 = xw8[(size_t)s0 * 32 + q];
        uint32 v1 = xw8[(size_t)s1 * 32 + q];
        uint32 v2 = xw8[(size_t)s2 * 32 + q];
        uint32 v3 = xw8[(size_t)s3 * 32 + q];
        uint32 v4 = xw8[(size_t)s4 * 32 + q];
        uint32 v5 = xw8[(size_t)s5 * 32 + q];
        uint32 v6 = xw8[(size_t)s6 * 32 + q];
        uint32 v7 = xw8[(size_t)s7 * 32 + q];
        acc_fp8x4(v0, a0, a1, a2, a3);
        acc_fp8x4(v1, a0, a1, a2, a3);
        acc_fp8x4(v2, a0, a1, a2, a3);
        acc_fp8x4(v3, a0, a1, a2, a3);
        acc_fp8x4(v4, a0, a1, a2, a3);
        acc_fp8x4(v5, a0, a1, a2, a3);
        acc_fp8x4(v6, a0, a1, a2, a3);
        acc_fp8x4(v7, a0, a1, a2, a3);
    }
    if (j < end) {   // 8 remaining
        int s0 = ep[j + hf];
        int s1 = ep[j + 2 + hf];
        int s2 = ep[j + 4 + hf];
        int s3 = ep[j + 6 + hf];
        uint32 v0 = xw8[(size_t)s0 * 32 + q];
        uint32 v1 = xw8[(size_t)s1 * 32 + q];
        uint32 v2 = xw8[(size_t)s2 * 32 + q];
        uint32 v3 = xw8[(size_t)s3 * 32 + q];
        acc_fp8x4(v0, a0, a1, a2, a3);
        acc_fp8x4(v1, a0, a1, a2, a3);
        acc_fp8x4(v2, a0, a1, a2, a3);
        acc_fp8x4(v3, a0, a1, a2, a3);
    }
    a0 += __shfl_xor(a0, 32);
    a1 += __shfl_xor(a1, 32);
    a2 += __shfl_xor(a2, 32);
    a3 += __shfl_xor(a3, 32);
    if (hf == 0) {
        float dv = dinv[node];
        float4 bb = *(const float4*)&b1[q * 4];
        float r0 = fmaxf(fmaf(dv, a0, bb.x), 0.f);
        float r1 = fmaxf(fmaf(dv, a1, bb.y), 0.f);
        float r2 = fmaxf(fmaf(dv, a2, bb.z), 0.f);
        float r3 = fmaxf(fmaf(dv, a3, bb.w), 0.f);
        union { __half2 h2[2]; uint2 u; } p;
        p.h2[0] = __floats2half2_rn(r0, r1);
        p.h2[1] = __floats2half2_rn(r2, r3);
        *(uint2*)&h[(size_t)node * HD + q * 4] = p.u;
    }
}

// ---------- GEMM2 (MFMA, no LDS): xw2q[N+1,16 dwords] row-scaled int8 ----------
// Row: dwords 0-11 = 48 int8 cols, dword 12 = f32 scale, 13-15 pad. 64B/row.

__global__ __launch_bounds__(256) void gemm2(const uint32* __restrict__ hh,
                                             const uint32* __restrict__ w2f,
                                             const float* __restrict__ dinv,
                                             uint32* __restrict__ xw2q) {
    int tx = threadIdx.x;
    int l = tx & 63, w = tx >> 6;
    int m = l & 15, oct = l >> 4;
    size_t node0 = (size_t)blockIdx.x * 128 + (size_t)w * 32;
    size_t nA = node0 + m;
    size_t nB = node0 + 16 + m;

    f32x4 acc0[3], acc1[3];
#pragma unroll
    for (int nt = 0; nt < 3; ++nt) {
        acc0[nt] = (f32x4){0.f, 0.f, 0.f, 0.f};
        acc1[nt] = (f32x4){0.f, 0.f, 0.f, 0.f};
    }

#pragma unroll
    for (int ks = 0; ks < 4; ++ks) {
        union { uint4 u; f16x8 h; } b0, b1;
        b0.u = (nA < (size_t)N) ? *(const uint4*)&hh[nA * 64 + ks * 16 + oct * 4]
                                : make_uint4(0u, 0u, 0u, 0u);
        b1.u = (nB < (size_t)N) ? *(const uint4*)&hh[nB * 64 + ks * 16 + oct * 4]
                                : make_uint4(0u, 0u, 0u, 0u);
#pragma unroll
        for (int nt = 0; nt < 3; ++nt) {
            union { uint4 u; f16x8 h; } a;
            a.u = *(const uint4*)&w2f[(nt * 4 + ks) * 256 + l * 4];
            acc0[nt] = __builtin_amdgcn_mfma_f32_16x16x32_f16(a.h, b0.h, acc0[nt], 0, 0, 0);
            acc1[nt] = __builtin_amdgcn_mfma_f32_16x16x32_f16(a.h, b1.h, acc1[nt], 0, 0, 0);
        }
    }

    // scale accumulators by dinv, find rowmax across octs, quantize int8
    float vA[12], vB[12];
    float dvA = (nA < (size_t)N) ? dinv[nA] : 0.f;
    float dvB = (nB < (size_t)N) ? dinv[nB] : 0.f;
    float mxA = 0.f, mxB = 0.f;
#pragma unroll
    for (int nt = 0; nt < 3; ++nt) {
#pragma unroll
        for (int i = 0; i < 4; ++i) {
            float a = acc0[nt][i] * dvA;
            float b = acc1[nt][i] * dvB;
            vA[nt * 4 + i] = a; vB[nt * 4 + i] = b;
            mxA = fmaxf(mxA, fabsf(a));
            mxB = fmaxf(mxB, fabsf(b));
        }
    }
    mxA = fmaxf(mxA, __shfl_xor(mxA, 16)); mxA = fmaxf(mxA, __shfl_xor(mxA, 32));
    mxB = fmaxf(mxB, __shfl_xor(mxB, 16)); mxB = fmaxf(mxB, __shfl_xor(mxB, 32));
    float scA = mxA * (1.f / 127.f), invA = (mxA > 0.f) ? 127.f / mxA : 0.f;
    float scB = mxB * (1.f / 127.f), invB = (mxB > 0.f) ? 127.f / mxB : 0.f;

    if (nA <= (size_t)N) {
#pragma unroll
        for (int nt = 0; nt < 3; ++nt) {
            uint32 p = 0;
#pragma unroll
            for (int i = 0; i < 4; ++i) {
                int qv = __float2int_rn(vA[nt * 4 + i] * invA);
                p |= ((uint32)qv & 255u) << (8 * i);
            }
            xw2q[nA * 16 + nt * 4 + oct] = p;
        }
        if (oct == 0) xw2q[nA * 16 + 12] = __float_as_uint(scA);
    }
    if (nB <= (size_t)N) {
#pragma unroll
        for (int nt = 0; nt < 3; ++nt) {
            uint32 p = 0;
#pragma unroll
            for (int i = 0; i < 4; ++i) {
                int qv = __float2int_rn(vB[nt * 4 + i] * invB);
                p |= ((uint32)qv & 255u) << (8 * i);
            }
            xw2q[nB * 16 + nt * 4 + oct] = p;
        }
        if (oct == 0) xw2q[nB * 16 + 12] = __float_as_uint(scB);
    }
}

// ---------- agg2: out[n] = b2 + dinv[n] * sum_j dequant(xw2q[src_j]) ----------
// 16 lanes per edge (64B row = 1 line), 4 edges/step, 16-edge unroll + 8 tail.

__global__ __launch_bounds__(256) void agg2(const uint32* __restrict__ xw2q,
                                            const int* __restrict__ rowptr,
                                            const int* __restrict__ rowend,
                                            const int* __restrict__ ep,
                                            const float* __restrict__ dinv,
                                            const float* __restrict__ b2,
                                            float* __restrict__ out) {
    int node = blockIdx.x * 4 + (threadIdx.x >> 6);
    if (node >= N) return;
    int lane = threadIdx.x & 63;
    int g = lane >> 4;       // edge group 0..3
    int q = lane & 15;       // dword within 64B row
    int sl = (lane & 48) | 12;   // lane holding the scale dword of this group
    int beg = rowptr[node], end = rowend[node];   // cap, multiple of 8
    float a0 = 0.f, a1 = 0.f, a2 = 0.f, a3 = 0.f;
    int j = beg;
    for (; j + 16 <= end; j += 16) {
        int s0 = ep[j + g];
        int s1 = ep[j + 4 + g];
        int s2 = ep[j + 8 + g];
        int s3 = ep[j + 12 + g];
        uint32 v0 = xw2q[(size_t)s0 * 16 + q];
        uint32 v1 = xw2q[(size_t)s1 * 16 + q];
        uint32 v2 = xw2q[(size_t)s2 * 16 + q];
        uint32 v3 = xw2q[(size_t)s3 * 16 + q];
        float c0 = __uint_as_float(__shfl((int)v0, sl));
        float c1 = __uint_as_float(__shfl((int)v1, sl));
        float c2 = __uint_as_float(__shfl((int)v2, sl));
        float c3 = __uint_as_float(__shfl((int)v3, sl));
        a0 = fmaf(c0, (float)((int)(v0 << 24) >> 24), a0);
        a1 = fmaf(c0, (float)((int)(v0 << 16) >> 24), a1);
        a2 = fmaf(c0, (float)((int)(v0 <<  8) >> 24), a2);
        a3 = fmaf(c0, (float)((int)v0 >> 24),         a3);
        a0 = fmaf(c1, (float)((int)(v1 << 24) >> 24), a0);
        a1 = fmaf(c1, (float)((int)(v1 << 16) >> 24), a1);
        a2 = fmaf(c1, (float)((int)(v1 <<  8) >> 24), a2);
        a3 = fmaf(c1, (float)((int)v1 >> 24),         a3);
        a0 = fmaf(c2, (float)((int)(v2 << 24) >> 24), a0);
        a1 = fmaf(c2, (float)((int)(v2 << 16) >> 24), a1);
        a2 = fmaf(c2, (float)((int)(v2 <<  8) >> 24), a2);
        a3 = fmaf(c2, (float)((int)v2 >> 24),         a3);
        a0 = fmaf(c3, (float)((int)(v3 << 24) >> 24), a0);
        a1 = fmaf(c3, (float)((int)(v3 << 16) >> 24), a1);
        a2 = fmaf(c3, (float)((int)(v3 <<  8) >> 24), a2);
        a3 = fmaf(c3, (float)((int)v3 >> 24),         a3);
    }
    if (j < end) {   // 8 remaining
        int s0 = ep[j + g];
        int s1 = ep[j + 4 + g];
        uint32 v0 = xw2q[(size_t)s0 * 16 + q];
        uint32 v1 = xw2q[(size_t)s1 * 16 + q];
        float c0 = __uint_as_float(__shfl((int)v0, sl));
        float c1 = __uint_as_float(__shfl((int)v1, sl));
        a0 = fmaf(c0, (float)((int)(v0 << 24) >> 24), a0);
        a1 = fmaf(c0, (float)((int)(v0 << 16) >> 24), a1);
        a2 = fmaf(c0, (float)((int)(v0 <<  8) >> 24), a2);
        a3 = fmaf(c0, (float)((int)v0 >> 24),         a3);
        a0 = fmaf(c1, (float)((int)(v1 << 24) >> 24), a0);
        a1 = fmaf(c1, (float)((int)(v1 << 16) >> 24), a1);
        a2 = fmaf(c1, (float)((int)(v1 <<  8) >> 24), a2);
        a3 = fmaf(c1, (float)((int)v1 >> 24),         a3);
    }
    // combine the 4 edge groups (bits 4-5 of lane)
    a0 += __shfl_xor(a0, 16); a0 += __shfl_xor(a0, 32);
    a1 += __shfl_xor(a1, 16); a1 += __shfl_xor(a1, 32);
    a2 += __shfl_xor(a2, 16); a2 += __shfl_xor(a2, 32);
    a3 += __shfl_xor(a3, 16); a3 += __shfl_xor(a3, 32);
    if (g == 0 && q < 12) {
        float dv = dinv[node];
        int c = q * 4;
        out[(size_t)node * C + c]     = fmaf(dv, a0, b2[c]);
        out[(size_t)node * C + c + 1] = fmaf(dv, a1, b2[c + 1]);
        out[(size_t)node * C + c + 2] = fmaf(dv, a2, b2[c + 2]);
        if (c + 3 < C)
            out[(size_t)node * C + c + 3] = fmaf(dv, a3, b2[c + 3]);
    }
}

extern "C" void kernel_launch(void* const* d_in, const int* in_sizes, int n_in,
                              void* d_out, int out_size, void* d_ws, size_t ws_size,
                              hipStream_t stream) {
    const float* x  = (const float*)d_in[0];
    const int*   ei = (const int*)d_in[1];
    const float* W1 = (const float*)d_in[2];
    const float* b1 = (const float*)d_in[3];
    const float* W2 = (const float*)d_in[4];
    const float* b2 = (const float*)d_in[5];
    float* out = (float*)d_out;

    size_t off = 0;
    auto alloc = [&](size_t bytes) {
        void* p = (char*)d_ws + off;
        off += (bytes + 255) & ~(size_t)255;
        return p;
    };
    int*    gmeta   = (int*)alloc((size_t)(NBUCK + 64) * 4);  // gbcur[NBUCK] + galloc
    uint32* pairs   = (uint32*)alloc((size_t)NBUCK * BCAP * 4);   // 12.8 MB
    int*    rowptr  = (int*)alloc((size_t)N * 4);
    int*    rowend  = (int*)alloc((size_t)N * 4);
    float*  dinv    = (float*)alloc((size_t)N * 4);
    int*    ep      = (int*)alloc((size_t)EN_CAP * 4);
    uint32* w1f     = (uint32*)alloc((size_t)W1F * 4);            // 32 KB frag table
    uint32* w2f     = (uint32*)alloc((size_t)W2F * 4);            // 12 KB frag table
    uint32* xw8     = (uint32*)alloc((size_t)(N + 1) * 32 * 4);   // fp8 [N+1][128]
    __half* hh      = (__half*)alloc((size_t)N * HD * 2);
    uint32* xw2q    = (uint32*)alloc((size_t)(N + 1) * 16 * 4);   // int8+scale [N+1][64B]
    (void)ws_size;
    int* gbcur  = gmeta;
    int* galloc = gmeta + NBUCK;

    hipMemsetAsync(gmeta, 0, (size_t)(NBUCK + 1) * 4, stream);
    prep_frags<<<(W1F + W2F + 255) / 256, 256, 0, stream>>>(W1, W2, w1f, w2f);
    bucket_scatter2<<<ABLK, 256, 0, stream>>>(ei, gbcur, pairs);
    bucket_countplace<<<NBUCK, 256, 0, stream>>>(pairs, gbcur, galloc,
                                                 rowptr, rowend, dinv, ep);

    gemm1<<<(N + 128) / 128, 256, 0, stream>>>(x, w1f, dinv, xw8);   // covers node N
    agg1<<<(N + 3) / 4, 256, 0, stream>>>(xw8, rowptr, rowend, ep, dinv, b1, hh);
    gemm2<<<(N + 128) / 128, 256, 0, stream>>>((const uint32*)hh, w2f, dinv, xw2q);
    agg2<<<(N + 3) / 4, 256, 0, stream>>>(xw2q, rowptr, rowend, ep, dinv, b2, out);
}